// Round 3
// baseline (235.817 us; speedup 1.0000x reference)
//
#include <hip/hip_runtime.h>

// SuperDCFrontShareLayer — complex Givens-like pair transform.
//   out[r][0]      = (x[r][0], 0)
//   out[r][1+2j]   = (t_j * x[r][1+2j], k_j * x[r][2+2j])   j in [0, n)
//   out[r][2+2j]   = (t_j * x[r][2+2j], k_j * x[r][1+2j])
//   out[r][c]      = (x[r][c], 0)  for c >= 1+2n
// k_j = sqrt(1 - t_j^2 + 1e-6). Reference output is complex64.
//
// The harness may represent the complex64 output either as interleaved fp32
// pairs (out_size = rows*2048) or as real-part fp32 (out_size = rows*1024,
// astype semantics). We branch on out_size HOST-side and write exactly
// out_size floats — the R1/R2 aborts were almost certainly OOB writes from
// assuming the interleaved size. n comes from in_sizes[1] (= len(weight) =
// sample_arch), so no device-side scalar read is needed.

#define COLS 1024
#define TPR  512   // threads per row (one per input col-pair)
#define TPB  256

__global__ __launch_bounds__(TPB) void sdc_interleaved(
    const float* __restrict__ x, const float* __restrict__ w,
    float* __restrict__ out, int n)
{
    const int idx = blockIdx.x * TPB + threadIdx.x;
    const int row = idx >> 9;            // / TPR
    const int t   = idx & (TPR - 1);

    const float* xr   = x   + (size_t)row * COLS;
    float*       orow = out + (size_t)row * (2 * COLS);

    const int a = 2 * t + 1;             // <= 1023
    const int b = a + 1;                 // <= 1024 (guarded below)
    const float xa = xr[a];

    if (t < n) {                         // n <= 511 -> b <= 1022 here
        const float xb = xr[b];
        const float tj = w[t];
        const float kj = sqrtf(1.0f - tj * tj + 1e-6f);
        *(float2*)(orow + 2 * a) = make_float2(tj * xa, kj * xb);  // 8B-aligned
        *(float2*)(orow + 2 * b) = make_float2(tj * xb, kj * xa);  // 16B-aligned
    } else {
        *(float2*)(orow + 2 * a) = make_float2(xa, 0.0f);
        if (b < COLS)
            *(float2*)(orow + 2 * b) = make_float2(xr[b], 0.0f);
    }
    if (t == 0)
        *(float2*)orow = make_float2(xr[0], 0.0f);   // col 0 pass-through
}

__global__ __launch_bounds__(TPB) void sdc_realonly(
    const float* __restrict__ x, const float* __restrict__ w,
    float* __restrict__ out, int n)
{
    const int idx = blockIdx.x * TPB + threadIdx.x;
    const int row = idx >> 9;
    const int t   = idx & (TPR - 1);

    const float* xr   = x   + (size_t)row * COLS;
    float*       orow = out + (size_t)row * COLS;

    const int a = 2 * t + 1;
    const int b = a + 1;
    const float xa = xr[a];

    if (t < n) {
        const float tj = w[t];
        orow[a] = tj * xa;
        orow[b] = tj * xr[b];
    } else {
        orow[a] = xa;
        if (b < COLS)
            orow[b] = xr[b];
    }
    if (t == 0)
        orow[0] = xr[0];
}

extern "C" void kernel_launch(void* const* d_in, const int* in_sizes, int n_in,
                              void* d_out, int out_size, void* d_ws, size_t ws_size,
                              hipStream_t stream) {
    const float* x   = (const float*)d_in[0];
    const float* w   = (const float*)d_in[1];
    float*       out = (float*)d_out;

    const int rows   = in_sizes[0] / COLS;   // 32768
    const int n      = in_sizes[1];          // 511 == sample_arch
    const int blocks = (rows * TPR) / TPB;   // 65536

    if (out_size >= rows * 2 * COLS) {
        sdc_interleaved<<<blocks, TPB, 0, stream>>>(x, w, out, n);
    } else {
        sdc_realonly<<<blocks, TPB, 0, stream>>>(x, w, out, n);
    }
}